// Round 9
// baseline (727.035 us; speedup 1.0000x reference)
//
#include <hip/hip_runtime.h>
#include <math.h>
#include <float.h>

#define DIM 256
#define MARGIN 0.125f
// Tie policy (verified PASS in R6/R7/R8 — do not change):
#define EPS_TIE 1e-4
#define PREFER_LOWER 1

#define ROWS 32   // rows per block (MFMA path): 4 waves share rows, split cols

typedef __attribute__((ext_vector_type(8))) short short8;   // 8 bf16 = 4 VGPR
typedef __attribute__((ext_vector_type(4))) float f32x4;    // MFMA acc

__device__ __forceinline__ unsigned short f32_to_bf16_rne(float f) {
    unsigned int u = __float_as_uint(f);
    u += 0x7fffu + ((u >> 16) & 1u);
    return (unsigned short)(u >> 16);
}
__device__ __forceinline__ float bf16_to_f32(unsigned short h) {
    return __uint_as_float((unsigned int)h << 16);
}

// async global->LDS, 16B/lane: LDS dest = wave-uniform base + lane*16 (HW rule)
__device__ __forceinline__ void stage16(const void* gsrc, void* ldst) {
    __builtin_amdgcn_global_load_lds(
        (const __attribute__((address_space(1))) unsigned int*)gsrc,
        (__attribute__((address_space(3))) unsigned int*)ldst,
        16, 0, 0);
}

// |e_j|^2 (fast pass only needs approx); one wave per codebook row
__global__ void esq_kernel(const float* __restrict__ embed, float* __restrict__ esq) {
    const int j = blockIdx.x;
    const int lane = threadIdx.x;  // 64
    float4 v = *reinterpret_cast<const float4*>(embed + (size_t)j * DIM + lane * 4);
    float s = v.x * v.x + v.y * v.y + v.z * v.z + v.w * v.w;
#pragma unroll
    for (int m = 32; m >= 1; m >>= 1) s += __shfl_xor(s, m, 64);
    if (lane == 0) esq[j] = s;
}

// embed -> fragment-major bf16 hi/lo for mfma_f32_16x16x32_bf16 B operand.
// Block b = ct*8 + s (ct: 16-col tile 0..63, s: 32-k step 0..7). Lane l holds
// col = ct*16 + (l&15), k = s*32 + (l>>4)*8 + i  (i=0..7), stored contiguous.
__global__ void efrag_kernel(const float* __restrict__ embed,
                             unsigned short* __restrict__ ehi,
                             unsigned short* __restrict__ elo) {
    const int b = blockIdx.x;          // 0..511
    const int l = threadIdx.x;         // 0..63
    const int ct = b >> 3, s = b & 7;
    const int col = ct * 16 + (l & 15);
    const int kb  = s * 32 + (l >> 4) * 8;
    const float* src = embed + (size_t)col * DIM + kb;
    float4 v0 = *reinterpret_cast<const float4*>(src);
    float4 v1 = *reinterpret_cast<const float4*>(src + 4);
    float vv[8] = {v0.x, v0.y, v0.z, v0.w, v1.x, v1.y, v1.z, v1.w};
    unsigned short hh[8], ll[8];
#pragma unroll
    for (int i = 0; i < 8; ++i) {
        unsigned short h = f32_to_bf16_rne(vv[i]);
        hh[i] = h;
        ll[i] = f32_to_bf16_rne(vv[i] - bf16_to_f32(h));
    }
    size_t base = ((size_t)b * 64 + l) * 8;
#pragma unroll
    for (int i = 0; i < 8; ++i) { ehi[base + i] = hh[i]; elo[base + i] = ll[i]; }
}

// ---- MFMA fast pass, LDS-staged B (2-phase dbuf), ct-split waves ----
// Block: 256 thr = 4 waves; all waves share ROWS=32 rows; wave w owns the
// 16-col quarter ct=w of every 64-col chunk. B staged per (jc,s) step via
// global_load_lds into bfrag[2] (8 KB/step, shared), barrier per step.
__global__ __launch_bounds__(256, 3)
void vq_mfma_kernel(const float* __restrict__ x, const float* __restrict__ embed,
                    const unsigned short* __restrict__ ehi,
                    const unsigned short* __restrict__ elo,
                    const float* __restrict__ esq, float* __restrict__ out,
                    int N, int K) {
    __shared__ unsigned short bfrag[2][4][2][512];  // [buf][ct][hi/lo][64 lanes x 8] = 16 KB
    __shared__ float  esq_lds[1024];
    __shared__ float  mv1[4][ROWS], mv2[4][ROWS];
    __shared__ int    mi1[4][ROWS];
    __shared__ int    rowidx[ROWS];
    __shared__ double rv1[256], rv2[256];
    __shared__ int    ri1[256], ri2[256];
    __shared__ float  xrow[DIM];
    __shared__ int    flr[ROWS];
    __shared__ int    nflag;

    const int t  = threadIdx.x;
    const int w  = t >> 6;       // wave = owned ct quarter
    const int l  = t & 63;
    const int ar = l & 15;       // A-row / B-col / C-col lane field
    const int ag = l >> 4;       // k-group / C-row-group lane field
    const int row0 = blockIdx.x * ROWS;

    if (t == 0) nflag = 0;
    for (int i = t; i < 1024; i += 256) esq_lds[i] = esq[i];

    // A fragments resident: 2 row-tiles x 8 k-steps, hi+lo (128 VGPR)
    short8 ahi[2][8], alo[2][8];
#pragma unroll
    for (int rt = 0; rt < 2; ++rt)
#pragma unroll
        for (int s = 0; s < 8; ++s) {
            const float* src = x + (size_t)(row0 + rt * 16 + ar) * DIM + s * 32 + ag * 8;
            float4 v0 = *reinterpret_cast<const float4*>(src);
            float4 v1 = *reinterpret_cast<const float4*>(src + 4);
            float vv[8] = {v0.x, v0.y, v0.z, v0.w, v1.x, v1.y, v1.z, v1.w};
#pragma unroll
            for (int i = 0; i < 8; ++i) {
                unsigned short h = f32_to_bf16_rne(vv[i]);
                ahi[rt][s][i] = (short)h;
                alo[rt][s][i] = (short)f32_to_bf16_rne(vv[i] - bf16_to_f32(h));
            }
        }

#define STAGE(CB, JC, S) do {                                                   \
        size_t go_ = (((size_t)((JC) * 4 + w) * 8 + (S)) * 64 + l) * 8;         \
        stage16(ehi + go_, &bfrag[CB][w][0][0]);                                \
        stage16(elo + go_, &bfrag[CB][w][1][0]);                                \
    } while (0)

    // prologue: stage (jc=0,s=0) into buf 0; barrier also publishes esq_lds/nflag
    STAGE(0, 0, 0);
    __syncthreads();

    float minv[8], min2v[8]; int mini[8];
#pragma unroll
    for (int i = 0; i < 8; ++i) { minv[i] = INFINITY; min2v[i] = INFINITY; mini[i] = 0; }

    f32x4 acc0 = (f32x4)0.0f, acc1 = (f32x4)0.0f;

    for (int jc = 0; jc < 16; ++jc) {
#pragma unroll
        for (int s = 0; s < 8; ++s) {           // unrolled: s, buf parity static
            const int cb = s & 1;
            if (s < 7)            STAGE(cb ^ 1, jc, s + 1);
            else if (jc < 15)     STAGE(cb ^ 1, jc + 1, 0);
            short8 bh = *reinterpret_cast<const short8*>(&bfrag[cb][w][0][l * 8]);
            short8 bl = *reinterpret_cast<const short8*>(&bfrag[cb][w][1][l * 8]);
            acc0 = __builtin_amdgcn_mfma_f32_16x16x32_bf16(ahi[0][s], bh, acc0, 0, 0, 0);
            acc0 = __builtin_amdgcn_mfma_f32_16x16x32_bf16(ahi[0][s], bl, acc0, 0, 0, 0);
            acc0 = __builtin_amdgcn_mfma_f32_16x16x32_bf16(alo[0][s], bh, acc0, 0, 0, 0);
            acc1 = __builtin_amdgcn_mfma_f32_16x16x32_bf16(ahi[1][s], bh, acc1, 0, 0, 0);
            acc1 = __builtin_amdgcn_mfma_f32_16x16x32_bf16(ahi[1][s], bl, acc1, 0, 0, 0);
            acc1 = __builtin_amdgcn_mfma_f32_16x16x32_bf16(alo[1][s], bh, acc1, 0, 0, 0);
            __syncthreads();    // drains stage of buf^1 + all reads of buf
        }
        // jc epilogue: scores + per-lane top-2 (col ascending in jc per lane)
        const int col = jc * 64 + w * 16 + ar;
        const float eq = esq_lds[col];
#pragma unroll
        for (int r = 0; r < 4; ++r) {
            float sc = fmaf(-2.0f, acc0[r], eq);
            if (sc < minv[r]) { min2v[r] = minv[r]; minv[r] = sc; mini[r] = col; }
            else if (sc < min2v[r]) min2v[r] = sc;
        }
#pragma unroll
        for (int r = 0; r < 4; ++r) {
            float sc = fmaf(-2.0f, acc1[r], eq);
            int ii = 4 + r;
            if (sc < minv[ii]) { min2v[ii] = minv[ii]; minv[ii] = sc; mini[ii] = col; }
            else if (sc < min2v[ii]) min2v[ii] = sc;
        }
        acc0 = (f32x4)0.0f; acc1 = (f32x4)0.0f;
    }
#undef STAGE

    // butterfly top-2 across the 16 ar lanes (masks 1,2,4,8); ties -> lower index
#pragma unroll
    for (int ii = 0; ii < 8; ++ii) {
        float v1 = minv[ii]; int i1 = mini[ii]; float v2 = min2v[ii];
#pragma unroll
        for (int m = 1; m < 16; m <<= 1) {
            float ov1 = __shfl_xor(v1, m, 64);
            int   oi1 = __shfl_xor(i1, m, 64);
            float ov2 = __shfl_xor(v2, m, 64);
            float nv2 = fminf(fmaxf(v1, ov1), fminf(v2, ov2));
            if (ov1 < v1 || (ov1 == v1 && oi1 < i1)) { v1 = ov1; i1 = oi1; }
            v2 = nv2;
        }
        minv[ii] = v1; mini[ii] = i1; min2v[ii] = v2;
    }
    // publish wave-level top-2 (its 256-col subset) per row
    if (ar == 0) {
#pragma unroll
        for (int ii = 0; ii < 8; ++ii) {
            int rr = (ii >> 2) * 16 + ag * 4 + (ii & 3);   // local row 0..31
            mv1[w][rr] = minv[ii]; mi1[w][rr] = mini[ii]; mv2[w][rr] = min2v[ii];
        }
    }
    __syncthreads();
    // cross-wave merge (full 1024-col top-2) + flagging
    if (t < ROWS) {
        float v1 = mv1[0][t]; int i1 = mi1[0][t]; float v2 = mv2[0][t];
#pragma unroll
        for (int ww = 1; ww < 4; ++ww) {
            float ov1 = mv1[ww][t]; int oi1 = mi1[ww][t]; float ov2 = mv2[ww][t];
            float nv2 = fminf(fmaxf(v1, ov1), fminf(v2, ov2));
            if (ov1 < v1 || (ov1 == v1 && oi1 < i1)) { v1 = ov1; i1 = oi1; }
            v2 = nv2;
        }
        rowidx[t] = i1;
        if (v2 - v1 < MARGIN) {            // ambiguous at fast-pass accuracy
            int p = atomicAdd(&nflag, 1);  // LDS atomic; p < ROWS
            flr[p] = t;
        }
    }
    __syncthreads();

    // outputs: [quantize | indices(as float) | residual] — 4 rows/round x 64 lanes
    const size_t IOFF = (size_t)N * DIM;
    const size_t ROFF = IOFF + (size_t)N;
#pragma unroll
    for (int rg = 0; rg < 8; ++rg) {
        const int rr  = rg * 4 + w;
        const int row = row0 + rr;
        const int idx = rowidx[rr];
        if (l == 0) out[IOFF + row] = (float)idx;
        float4 e  = *reinterpret_cast<const float4*>(embed + (size_t)idx * DIM + l * 4);
        float4 xv = *reinterpret_cast<const float4*>(x + (size_t)row * DIM + l * 4);
        *reinterpret_cast<float4*>(out + (size_t)row * DIM + l * 4) = e;
        float4 rv = make_float4(e.x - xv.x, e.y - xv.y, e.z - xv.z, e.w - xv.w);
        *reinterpret_cast<float4*>(out + ROFF + (size_t)row * DIM + l * 4) = rv;
    }

    // ---- exact (fp64) top-2 refinement + tie policy (R6-verified, unchanged) ----
    __syncthreads();
    const int nf = nflag;
    for (int f = 0; f < nf; ++f) {
        const int row = row0 + flr[f];
        if (t < 64) {
            float4 v = *reinterpret_cast<const float4*>(x + (size_t)row * DIM + t * 4);
            xrow[t * 4 + 0] = v.x; xrow[t * 4 + 1] = v.y;
            xrow[t * 4 + 2] = v.z; xrow[t * 4 + 3] = v.w;
        }
        __syncthreads();

        double v1 = DBL_MAX, v2 = DBL_MAX; int i1 = 0x7fffffff, i2 = 0x7fffffff;
#pragma unroll
        for (int jj = 0; jj < 4; ++jj) {
            const int j = t * 4 + jj;
            const float* e = embed + (size_t)j * DIM;
            double xe = 0.0, ee = 0.0;
            for (int kg = 0; kg < DIM / 4; ++kg) {
                float4 ev = *reinterpret_cast<const float4*>(e + kg * 4);
                double e0 = ev.x, e1 = ev.y, e2 = ev.z, e3 = ev.w;
                xe += e0 * (double)xrow[kg * 4 + 0] + e1 * (double)xrow[kg * 4 + 1]
                    + e2 * (double)xrow[kg * 4 + 2] + e3 * (double)xrow[kg * 4 + 3];
                ee += e0 * e0 + e1 * e1 + e2 * e2 + e3 * e3;
            }
            double d = ee - 2.0 * xe;            // shift-invariant score
            if (d < v1 || (d == v1 && j < i1)) { v2 = v1; i2 = i1; v1 = d; i1 = j; }
            else if (d < v2 || (d == v2 && j < i2)) { v2 = d; i2 = j; }
        }
        rv1[t] = v1; ri1[t] = i1; rv2[t] = v2; ri2[t] = i2;
        __syncthreads();
        for (int s = 128; s > 0; s >>= 1) {
            if (t < s) {
                double a1 = rv1[t],     a2 = rv2[t];     int k1 = ri1[t],     k2 = ri2[t];
                double b1 = rv1[t + s], b2 = rv2[t + s]; int j1 = ri1[t + s], j2 = ri2[t + s];
                double w1, w2; int m1, m2;
                bool bfirst = (b1 < a1) || (b1 == a1 && j1 < k1);
                if (bfirst) {
                    w1 = b1; m1 = j1;
                    if (a1 < b2 || (a1 == b2 && k1 < j2)) { w2 = a1; m2 = k1; }
                    else                                   { w2 = b2; m2 = j2; }
                } else {
                    w1 = a1; m1 = k1;
                    if (b1 < a2 || (b1 == a2 && j1 < k2)) { w2 = b1; m2 = j1; }
                    else                                   { w2 = a2; m2 = k2; }
                }
                rv1[t] = w1; ri1[t] = m1; rv2[t] = w2; ri2[t] = m2;
            }
            __syncthreads();
        }
        int idx = ri1[0];
        {
            const double gap = rv2[0] - rv1[0];
#if PREFER_LOWER
            if (gap < EPS_TIE && ri2[0] < ri1[0]) idx = ri2[0];
#else
            if (gap < EPS_TIE && ri2[0] > ri1[0]) idx = ri2[0];
#endif
        }
        if (t == 0) out[IOFF + row] = (float)idx;
        if (t < 64) {
            int d0 = t * 4;
            float4 e  = *reinterpret_cast<const float4*>(embed + (size_t)idx * DIM + d0);
            float4 xv = *reinterpret_cast<const float4*>(x + (size_t)row * DIM + d0);
            *reinterpret_cast<float4*>(out + (size_t)row * DIM + d0) = e;
            float4 rr = make_float4(e.x - xv.x, e.y - xv.y, e.z - xv.z, e.w - xv.w);
            *reinterpret_cast<float4*>(out + ROFF + (size_t)row * DIM + d0) = rr;
        }
        __syncthreads();
    }
}

// ================= fallback: R6-verified VALU path (used if ws too small) ====
#define BM 64
#define BN 64
#define DK 64
__global__ __launch_bounds__(256, 4)
void vq_argmin_kernel(const float* __restrict__ x, const float* __restrict__ embed,
                      const float* __restrict__ esq, float* __restrict__ out,
                      int N, int K) {
    __shared__ float xs[DK][BM];
    __shared__ float es[DK][BN];
    __shared__ double rv1[256], rv2[256];
    __shared__ int    ri1[256], ri2[256];
    __shared__ float  xrow[DIM];
    __shared__ int    flr[BM];
    __shared__ int    nflag;

    const int t = threadIdx.x;
    const int tx = t & 15, ty = t >> 4;
    const int row0 = blockIdx.x * BM;
    if (t == 0) nflag = 0;

    float minv[4], min2v[4]; int mini[4];
#pragma unroll
    for (int r = 0; r < 4; ++r) { minv[r] = INFINITY; min2v[r] = INFINITY; mini[r] = 0; }

    for (int jc = 0; jc < K / BN; ++jc) {
        float acc[4][4];
#pragma unroll
        for (int r = 0; r < 4; ++r)
#pragma unroll
            for (int c = 0; c < 4; ++c) acc[r][c] = 0.0f;
        for (int dc = 0; dc < DIM / DK; ++dc) {
            __syncthreads();
#pragma unroll
            for (int it = 0; it < 4; ++it) {
                int idx = t + 256 * it, r = idx & 63, kg = idx >> 6;
                float4 v = *reinterpret_cast<const float4*>(
                    x + (size_t)(row0 + r) * DIM + dc * DK + kg * 4);
                xs[kg*4+0][r] = v.x; xs[kg*4+1][r] = v.y; xs[kg*4+2][r] = v.z; xs[kg*4+3][r] = v.w;
            }
#pragma unroll
            for (int it = 0; it < 4; ++it) {
                int idx = t + 256 * it, c = idx & 63, kg = idx >> 6;
                float4 v = *reinterpret_cast<const float4*>(
                    embed + (size_t)(jc * BN + c) * DIM + dc * DK + kg * 4);
                es[kg*4+0][c] = v.x; es[kg*4+1][c] = v.y; es[kg*4+2][c] = v.z; es[kg*4+3][c] = v.w;
            }
            __syncthreads();
#pragma unroll
            for (int k = 0; k < DK; ++k) {
                float4 a = *reinterpret_cast<const float4*>(&xs[k][ty * 4]);
                float4 b = *reinterpret_cast<const float4*>(&es[k][tx * 4]);
                float arr[4] = {a.x, a.y, a.z, a.w}, bc[4] = {b.x, b.y, b.z, b.w};
#pragma unroll
                for (int r = 0; r < 4; ++r)
#pragma unroll
                    for (int c = 0; c < 4; ++c) acc[r][c] = fmaf(arr[r], bc[c], acc[r][c]);
            }
        }
        float4 eq = *reinterpret_cast<const float4*>(esq + jc * BN + tx * 4);
        float eqa[4] = {eq.x, eq.y, eq.z, eq.w};
#pragma unroll
        for (int c = 0; c < 4; ++c) {
            int j = jc * BN + tx * 4 + c;
#pragma unroll
            for (int r = 0; r < 4; ++r) {
                float s = fmaf(-2.0f, acc[r][c], eqa[c]);
                if (s < minv[r]) { min2v[r] = minv[r]; minv[r] = s; mini[r] = j; }
                else if (s < min2v[r]) { min2v[r] = s; }
            }
        }
    }
#pragma unroll
    for (int r = 0; r < 4; ++r) {
        float v1 = minv[r]; int i1 = mini[r]; float v2 = min2v[r];
#pragma unroll
        for (int m = 1; m < 16; m <<= 1) {
            float ov1 = __shfl_xor(v1, m, 64); int oi1 = __shfl_xor(i1, m, 64);
            float ov2 = __shfl_xor(v2, m, 64);
            float nv2 = fminf(fmaxf(v1, ov1), fminf(v2, ov2));
            if (ov1 < v1 || (ov1 == v1 && oi1 < i1)) { v1 = ov1; i1 = oi1; }
            v2 = nv2;
        }
        minv[r] = v1; mini[r] = i1; min2v[r] = v2;
    }
    const size_t IOFF = (size_t)N * DIM, ROFF = IOFF + (size_t)N;
#pragma unroll
    for (int r = 0; r < 4; ++r) {
        int row = row0 + ty * 4 + r, idx = mini[r];
        if (tx == 0) {
            out[IOFF + row] = (float)idx;
            if (min2v[r] - minv[r] < MARGIN) { int p = atomicAdd(&nflag, 1); flr[p] = ty * 4 + r; }
        }
#pragma unroll
        for (int g = 0; g < 4; ++g) {
            int d0 = tx * 16 + g * 4;
            float4 e  = *reinterpret_cast<const float4*>(embed + (size_t)idx * DIM + d0);
            float4 xv = *reinterpret_cast<const float4*>(x + (size_t)row * DIM + d0);
            *reinterpret_cast<float4*>(out + (size_t)row * DIM + d0) = e;
            float4 rr = make_float4(e.x - xv.x, e.y - xv.y, e.z - xv.z, e.w - xv.w);
            *reinterpret_cast<float4*>(out + ROFF + (size_t)row * DIM + d0) = rr;
        }
    }
    __syncthreads();
    const int nf = nflag;
    for (int f = 0; f < nf; ++f) {
        const int row = row0 + flr[f];
        if (t < 64) {
            float4 v = *reinterpret_cast<const float4*>(x + (size_t)row * DIM + t * 4);
            xrow[t*4+0] = v.x; xrow[t*4+1] = v.y; xrow[t*4+2] = v.z; xrow[t*4+3] = v.w;
        }
        __syncthreads();
        double v1 = DBL_MAX, v2 = DBL_MAX; int i1 = 0x7fffffff, i2 = 0x7fffffff;
#pragma unroll
        for (int jj = 0; jj < 4; ++jj) {
            const int j = t * 4 + jj;
            const float* e = embed + (size_t)j * DIM;
            double xe = 0.0, ee = 0.0;
            for (int kg = 0; kg < DIM / 4; ++kg) {
                float4 ev = *reinterpret_cast<const float4*>(e + kg * 4);
                double e0 = ev.x, e1 = ev.y, e2 = ev.z, e3 = ev.w;
                xe += e0*(double)xrow[kg*4+0] + e1*(double)xrow[kg*4+1]
                    + e2*(double)xrow[kg*4+2] + e3*(double)xrow[kg*4+3];
                ee += e0*e0 + e1*e1 + e2*e2 + e3*e3;
            }
            double d = ee - 2.0 * xe;
            if (d < v1 || (d == v1 && j < i1)) { v2 = v1; i2 = i1; v1 = d; i1 = j; }
            else if (d < v2 || (d == v2 && j < i2)) { v2 = d; i2 = j; }
        }
        rv1[t] = v1; ri1[t] = i1; rv2[t] = v2; ri2[t] = i2;
        __syncthreads();
        for (int s = 128; s > 0; s >>= 1) {
            if (t < s) {
                double a1 = rv1[t], a2 = rv2[t]; int k1 = ri1[t], k2 = ri2[t];
                double b1 = rv1[t+s], b2 = rv2[t+s]; int j1 = ri1[t+s], j2 = ri2[t+s];
                double w1, w2; int m1, m2;
                bool bfirst = (b1 < a1) || (b1 == a1 && j1 < k1);
                if (bfirst) { w1 = b1; m1 = j1;
                    if (a1 < b2 || (a1 == b2 && k1 < j2)) { w2 = a1; m2 = k1; } else { w2 = b2; m2 = j2; }
                } else { w1 = a1; m1 = k1;
                    if (b1 < a2 || (b1 == a2 && j1 < k2)) { w2 = b1; m2 = j1; } else { w2 = a2; m2 = k2; }
                }
                rv1[t] = w1; ri1[t] = m1; rv2[t] = w2; ri2[t] = m2;
            }
            __syncthreads();
        }
        int idx = ri1[0];
        const double gap = rv2[0] - rv1[0];
#if PREFER_LOWER
        if (gap < EPS_TIE && ri2[0] < ri1[0]) idx = ri2[0];
#else
        if (gap < EPS_TIE && ri2[0] > ri1[0]) idx = ri2[0];
#endif
        if (t == 0) out[IOFF + row] = (float)idx;
        if (t < 64) {
            int d0 = t * 4;
            float4 e  = *reinterpret_cast<const float4*>(embed + (size_t)idx * DIM + d0);
            float4 xv = *reinterpret_cast<const float4*>(x + (size_t)row * DIM + d0);
            *reinterpret_cast<float4*>(out + (size_t)row * DIM + d0) = e;
            float4 rr = make_float4(e.x - xv.x, e.y - xv.y, e.z - xv.z, e.w - xv.w);
            *reinterpret_cast<float4*>(out + ROFF + (size_t)row * DIM + d0) = rr;
        }
        __syncthreads();
    }
}

extern "C" void kernel_launch(void* const* d_in, const int* in_sizes, int n_in,
                              void* d_out, int out_size, void* d_ws, size_t ws_size,
                              hipStream_t stream) {
    const float* x     = (const float*)d_in[0];
    const float* embed = (const float*)d_in[1];
    float* out = (float*)d_out;
    const int N = in_sizes[0] / DIM;   // 65536
    const int K = in_sizes[1] / DIM;   // 1024

    // ws layout (MFMA path): [0,4KB) esq | [4KB, +512KB) ehi | [+512KB, +512KB) elo
    float* esq = (float*)d_ws;
    unsigned short* ehi = (unsigned short*)((char*)d_ws + 4096);
    unsigned short* elo = (unsigned short*)((char*)d_ws + 4096 + 524288);
    const size_t need = 4096 + 2 * 524288;

    esq_kernel<<<K, 64, 0, stream>>>(embed, esq);
    if (ws_size >= need) {
        efrag_kernel<<<(K / 16) * 8, 64, 0, stream>>>(embed, ehi, elo);
        vq_mfma_kernel<<<N / ROWS, 256, 0, stream>>>(x, embed, ehi, elo, esq, out, N, K);
    } else {
        vq_argmin_kernel<<<N / BM, 256, 0, stream>>>(x, embed, esq, out, N, K);
    }
}

// Round 10
// 582.453 us; speedup vs baseline: 1.2482x; 1.2482x over previous
//
#include <hip/hip_runtime.h>
#include <math.h>
#include <float.h>

#define DIM 256
#define MARGIN 0.125f
// Tie policy (verified PASS in R6/R7/R8/R9 — do not change):
#define EPS_TIE 1e-4
#define PREFER_LOWER 1

#define ROWS 128   // rows per block (MFMA path): 4 waves x 32 rows, col-shared

typedef __attribute__((ext_vector_type(8))) short short8;   // 8 bf16 = 4 VGPR
typedef __attribute__((ext_vector_type(4))) float f32x4;    // MFMA acc / vec4

__device__ __forceinline__ unsigned short f32_to_bf16_rne(float f) {
    unsigned int u = __float_as_uint(f);
    u += 0x7fffu + ((u >> 16) & 1u);
    return (unsigned short)(u >> 16);
}
__device__ __forceinline__ float bf16_to_f32(unsigned short h) {
    return __uint_as_float((unsigned int)h << 16);
}

// streaming (non-temporal) vec4 access: keep B/embed hot in L2
__device__ __forceinline__ f32x4 nt_load4(const float* p) {
    return __builtin_nontemporal_load((const f32x4*)p);
}
__device__ __forceinline__ void nt_store4(float* p, f32x4 v) {
    __builtin_nontemporal_store(v, (f32x4*)p);
}

// async global->LDS, 16B/lane: LDS dest = wave-uniform base + lane*16 (HW rule)
__device__ __forceinline__ void stage16(const void* gsrc, void* ldst) {
    __builtin_amdgcn_global_load_lds(
        (const __attribute__((address_space(1))) unsigned int*)gsrc,
        (__attribute__((address_space(3))) unsigned int*)ldst,
        16, 0, 0);
}

// |e_j|^2 (fast pass only needs approx); one wave per codebook row
__global__ void esq_kernel(const float* __restrict__ embed, float* __restrict__ esq) {
    const int j = blockIdx.x;
    const int lane = threadIdx.x;  // 64
    float4 v = *reinterpret_cast<const float4*>(embed + (size_t)j * DIM + lane * 4);
    float s = v.x * v.x + v.y * v.y + v.z * v.z + v.w * v.w;
#pragma unroll
    for (int m = 32; m >= 1; m >>= 1) s += __shfl_xor(s, m, 64);
    if (lane == 0) esq[j] = s;
}

// embed -> fragment-major bf16 hi/lo for mfma_f32_16x16x32_bf16 B operand.
// Block b = ct*8 + s (ct: 16-col tile 0..63, s: 32-k step 0..7). Lane l holds
// col = ct*16 + (l&15), k = s*32 + (l>>4)*8 + i  (i=0..7), stored contiguous.
__global__ void efrag_kernel(const float* __restrict__ embed,
                             unsigned short* __restrict__ ehi,
                             unsigned short* __restrict__ elo) {
    const int b = blockIdx.x;          // 0..511
    const int l = threadIdx.x;         // 0..63
    const int ct = b >> 3, s = b & 7;
    const int col = ct * 16 + (l & 15);
    const int kb  = s * 32 + (l >> 4) * 8;
    const float* src = embed + (size_t)col * DIM + kb;
    float4 v0 = *reinterpret_cast<const float4*>(src);
    float4 v1 = *reinterpret_cast<const float4*>(src + 4);
    float vv[8] = {v0.x, v0.y, v0.z, v0.w, v1.x, v1.y, v1.z, v1.w};
    unsigned short hh[8], ll[8];
#pragma unroll
    for (int i = 0; i < 8; ++i) {
        unsigned short h = f32_to_bf16_rne(vv[i]);
        hh[i] = h;
        ll[i] = f32_to_bf16_rne(vv[i] - bf16_to_f32(h));
    }
    size_t base = ((size_t)b * 64 + l) * 8;
#pragma unroll
    for (int i = 0; i < 8; ++i) { ehi[base + i] = hh[i]; elo[base + i] = ll[i]; }
}

// ---- MFMA fast pass: 4 waves x 32 rows, B LDS-staged (2-phase dbuf) ----
// Per (jc,s) step: wave w stages ct=w hi+lo (8 KB/block total) for step+1,
// then every wave reads ALL 4 ct fragments and does 24 MFMAs. One barrier per
// step; the staged loads land under the MFMA phase. B L2-traffic = 512 MB.
__global__ __launch_bounds__(256, 2)
void vq_mfma_kernel(const float* __restrict__ x, const float* __restrict__ embed,
                    const unsigned short* __restrict__ ehi,
                    const unsigned short* __restrict__ elo,
                    const float* __restrict__ esq, float* __restrict__ out,
                    int N, int K) {
    __shared__ unsigned short bfrag[2][4][2][512];  // [buf][ct][hi/lo][64x8] = 16 KB
    __shared__ float  esq_lds[1024];
    __shared__ double rv1[256], rv2[256];
    __shared__ int    ri1[256], ri2[256];
    __shared__ float  xrow[DIM];
    __shared__ int    flr[ROWS];
    __shared__ int    nflag;

    const int t  = threadIdx.x;
    const int w  = t >> 6;       // wave 0..3 (owns rows wrow0..wrow0+31; stages ct=w)
    const int l  = t & 63;
    const int ar = l & 15;       // A-row / B-col / C-col lane field
    const int ag = l >> 4;       // k-group / C-row-group lane field
    const int row0  = blockIdx.x * ROWS;
    const int wrow0 = row0 + w * 32;

    if (t == 0) nflag = 0;
    for (int i = t; i < 1024; i += 256) esq_lds[i] = esq[i];

    // A fragments resident: 2 row-tiles x 8 k-steps, hi+lo (128 VGPR); NT loads
    short8 ahi[2][8], alo[2][8];
#pragma unroll
    for (int rt = 0; rt < 2; ++rt)
#pragma unroll
        for (int s = 0; s < 8; ++s) {
            const float* src = x + (size_t)(wrow0 + rt * 16 + ar) * DIM + s * 32 + ag * 8;
            f32x4 v0 = nt_load4(src);
            f32x4 v1 = nt_load4(src + 4);
            float vv[8] = {v0[0], v0[1], v0[2], v0[3], v1[0], v1[1], v1[2], v1[3]};
#pragma unroll
            for (int i = 0; i < 8; ++i) {
                unsigned short h = f32_to_bf16_rne(vv[i]);
                ahi[rt][s][i] = (short)h;
                alo[rt][s][i] = (short)f32_to_bf16_rne(vv[i] - bf16_to_f32(h));
            }
        }

#define STAGE(CB, JC, S) do {                                                   \
        size_t go_ = (((size_t)((JC) * 4 + w) * 8 + (S)) * 64 + l) * 8;         \
        stage16(ehi + go_, &bfrag[CB][w][0][0]);                                \
        stage16(elo + go_, &bfrag[CB][w][1][0]);                                \
    } while (0)

    // prologue: stage (jc=0,s=0) into buf 0; barrier also publishes esq_lds/nflag
    STAGE(0, 0, 0);
    __syncthreads();

    float minv[8], min2v[8]; int mini[8];
#pragma unroll
    for (int i = 0; i < 8; ++i) { minv[i] = INFINITY; min2v[i] = INFINITY; mini[i] = 0; }

    f32x4 acc[2][4];
#pragma unroll
    for (int rt = 0; rt < 2; ++rt)
#pragma unroll
        for (int ct = 0; ct < 4; ++ct) acc[rt][ct] = (f32x4)0.0f;

    for (int jc = 0; jc < 16; ++jc) {
#pragma unroll
        for (int s = 0; s < 8; ++s) {          // unrolled: s, buf parity static
            const int cb = s & 1;
            if (s < 7)            STAGE(cb ^ 1, jc, s + 1);
            else if (jc < 15)     STAGE(cb ^ 1, jc + 1, 0);
            short8 bh[4], bl[4];
#pragma unroll
            for (int ct = 0; ct < 4; ++ct) {
                bh[ct] = *reinterpret_cast<const short8*>(&bfrag[cb][ct][0][l * 8]);
                bl[ct] = *reinterpret_cast<const short8*>(&bfrag[cb][ct][1][l * 8]);
            }
#pragma unroll
            for (int rt = 0; rt < 2; ++rt)
#pragma unroll
                for (int ct = 0; ct < 4; ++ct) {
                    acc[rt][ct] = __builtin_amdgcn_mfma_f32_16x16x32_bf16(
                        ahi[rt][s], bh[ct], acc[rt][ct], 0, 0, 0);
                    acc[rt][ct] = __builtin_amdgcn_mfma_f32_16x16x32_bf16(
                        ahi[rt][s], bl[ct], acc[rt][ct], 0, 0, 0);
                    acc[rt][ct] = __builtin_amdgcn_mfma_f32_16x16x32_bf16(
                        alo[rt][s], bh[ct], acc[rt][ct], 0, 0, 0);
                }
            __syncthreads();   // stage of buf^1 drained; reads of buf done
        }
        // jc epilogue: scores + per-lane top-2 (ct then jc ascending -> first-index)
#pragma unroll
        for (int rt = 0; rt < 2; ++rt)
#pragma unroll
            for (int ct = 0; ct < 4; ++ct) {
                const int col = jc * 64 + ct * 16 + ar;
                const float eq = esq_lds[col];
#pragma unroll
                for (int r = 0; r < 4; ++r) {
                    float sc = fmaf(-2.0f, acc[rt][ct][r], eq);
                    int ii = rt * 4 + r;
                    if (sc < minv[ii]) { min2v[ii] = minv[ii]; minv[ii] = sc; mini[ii] = col; }
                    else if (sc < min2v[ii]) min2v[ii] = sc;
                }
                acc[rt][ct] = (f32x4)0.0f;
            }
    }
#undef STAGE

    // butterfly top-2 across the 16 ar lanes (masks 1,2,4,8); ties -> lower index
#pragma unroll
    for (int ii = 0; ii < 8; ++ii) {
        float v1 = minv[ii]; int i1 = mini[ii]; float v2 = min2v[ii];
#pragma unroll
        for (int m = 1; m < 16; m <<= 1) {
            float ov1 = __shfl_xor(v1, m, 64);
            int   oi1 = __shfl_xor(i1, m, 64);
            float ov2 = __shfl_xor(v2, m, 64);
            float nv2 = fminf(fmaxf(v1, ov1), fminf(v2, ov2));
            if (ov1 < v1 || (ov1 == v1 && oi1 < i1)) { v1 = ov1; i1 = oi1; }
            v2 = nv2;
        }
        minv[ii] = v1; mini[ii] = i1; min2v[ii] = v2;
    }

    // outputs: [quantize | indices(as float) | residual]; NT streams for big writes
    const size_t IOFF = (size_t)N * DIM;
    const size_t ROFF = IOFF + (size_t)N;
#pragma unroll
    for (int ii = 0; ii < 8; ++ii) {
        const int rt = ii >> 2, r = ii & 3;
        const int row = wrow0 + rt * 16 + ag * 4 + r;
        const int idx = mini[ii];
        if (ar == 0) {
            out[IOFF + row] = (float)idx;
            if (min2v[ii] - minv[ii] < MARGIN) {
                int p = atomicAdd(&nflag, 1);      // LDS atomic; p < ROWS
                flr[p] = row - row0;
            }
        }
#pragma unroll
        for (int q = 0; q < 4; ++q) {
            int d0 = ar * 16 + q * 4;
            f32x4 e  = *reinterpret_cast<const f32x4*>(embed + (size_t)idx * DIM + d0);
            f32x4 xv = nt_load4(x + (size_t)row * DIM + d0);
            nt_store4(out + (size_t)row * DIM + d0, e);
            nt_store4(out + ROFF + (size_t)row * DIM + d0, e - xv);
        }
    }

    // ---- exact (fp64) top-2 refinement + tie policy (R6-verified, unchanged) ----
    __syncthreads();
    const int nf = nflag;
    for (int f = 0; f < nf; ++f) {
        const int row = row0 + flr[f];
        if (t < 64) {
            float4 v = *reinterpret_cast<const float4*>(x + (size_t)row * DIM + t * 4);
            xrow[t * 4 + 0] = v.x; xrow[t * 4 + 1] = v.y;
            xrow[t * 4 + 2] = v.z; xrow[t * 4 + 3] = v.w;
        }
        __syncthreads();

        double v1 = DBL_MAX, v2 = DBL_MAX; int i1 = 0x7fffffff, i2 = 0x7fffffff;
#pragma unroll
        for (int jj = 0; jj < 4; ++jj) {
            const int j = t * 4 + jj;
            const float* e = embed + (size_t)j * DIM;
            double xe = 0.0, ee = 0.0;
            for (int kg = 0; kg < DIM / 4; ++kg) {
                float4 ev = *reinterpret_cast<const float4*>(e + kg * 4);
                double e0 = ev.x, e1 = ev.y, e2 = ev.z, e3 = ev.w;
                xe += e0 * (double)xrow[kg * 4 + 0] + e1 * (double)xrow[kg * 4 + 1]
                    + e2 * (double)xrow[kg * 4 + 2] + e3 * (double)xrow[kg * 4 + 3];
                ee += e0 * e0 + e1 * e1 + e2 * e2 + e3 * e3;
            }
            double d = ee - 2.0 * xe;            // shift-invariant score
            if (d < v1 || (d == v1 && j < i1)) { v2 = v1; i2 = i1; v1 = d; i1 = j; }
            else if (d < v2 || (d == v2 && j < i2)) { v2 = d; i2 = j; }
        }
        rv1[t] = v1; ri1[t] = i1; rv2[t] = v2; ri2[t] = i2;
        __syncthreads();
        for (int s = 128; s > 0; s >>= 1) {
            if (t < s) {
                double a1 = rv1[t],     a2 = rv2[t];     int k1 = ri1[t],     k2 = ri2[t];
                double b1 = rv1[t + s], b2 = rv2[t + s]; int j1 = ri1[t + s], j2 = ri2[t + s];
                double w1, w2; int m1, m2;
                bool bfirst = (b1 < a1) || (b1 == a1 && j1 < k1);
                if (bfirst) {
                    w1 = b1; m1 = j1;
                    if (a1 < b2 || (a1 == b2 && k1 < j2)) { w2 = a1; m2 = k1; }
                    else                                   { w2 = b2; m2 = j2; }
                } else {
                    w1 = a1; m1 = k1;
                    if (b1 < a2 || (b1 == a2 && j1 < k2)) { w2 = b1; m2 = j1; }
                    else                                   { w2 = a2; m2 = k2; }
                }
                rv1[t] = w1; ri1[t] = m1; rv2[t] = w2; ri2[t] = m2;
            }
            __syncthreads();
        }
        int idx = ri1[0];
        {
            const double gap = rv2[0] - rv1[0];
#if PREFER_LOWER
            if (gap < EPS_TIE && ri2[0] < ri1[0]) idx = ri2[0];
#else
            if (gap < EPS_TIE && ri2[0] > ri1[0]) idx = ri2[0];
#endif
        }
        if (t == 0) out[IOFF + row] = (float)idx;
        if (t < 64) {
            int d0 = t * 4;
            float4 e  = *reinterpret_cast<const float4*>(embed + (size_t)idx * DIM + d0);
            float4 xv = *reinterpret_cast<const float4*>(x + (size_t)row * DIM + d0);
            *reinterpret_cast<float4*>(out + (size_t)row * DIM + d0) = e;
            float4 rr = make_float4(e.x - xv.x, e.y - xv.y, e.z - xv.z, e.w - xv.w);
            *reinterpret_cast<float4*>(out + ROFF + (size_t)row * DIM + d0) = rr;
        }
        __syncthreads();
    }
}

// ================= fallback: R6-verified VALU path (used if ws too small) ====
#define BM 64
#define BN 64
#define DK 64
__global__ __launch_bounds__(256, 4)
void vq_argmin_kernel(const float* __restrict__ x, const float* __restrict__ embed,
                      const float* __restrict__ esq, float* __restrict__ out,
                      int N, int K) {
    __shared__ float xs[DK][BM];
    __shared__ float es[DK][BN];
    __shared__ double rv1[256], rv2[256];
    __shared__ int    ri1[256], ri2[256];
    __shared__ float  xrow[DIM];
    __shared__ int    flr[BM];
    __shared__ int    nflag;

    const int t = threadIdx.x;
    const int tx = t & 15, ty = t >> 4;
    const int row0 = blockIdx.x * BM;
    if (t == 0) nflag = 0;

    float minv[4], min2v[4]; int mini[4];
#pragma unroll
    for (int r = 0; r < 4; ++r) { minv[r] = INFINITY; min2v[r] = INFINITY; mini[r] = 0; }

    for (int jc = 0; jc < K / BN; ++jc) {
        float acc[4][4];
#pragma unroll
        for (int r = 0; r < 4; ++r)
#pragma unroll
            for (int c = 0; c < 4; ++c) acc[r][c] = 0.0f;
        for (int dc = 0; dc < DIM / DK; ++dc) {
            __syncthreads();
#pragma unroll
            for (int it = 0; it < 4; ++it) {
                int idx = t + 256 * it, r = idx & 63, kg = idx >> 6;
                float4 v = *reinterpret_cast<const float4*>(
                    x + (size_t)(row0 + r) * DIM + dc * DK + kg * 4);
                xs[kg*4+0][r] = v.x; xs[kg*4+1][r] = v.y; xs[kg*4+2][r] = v.z; xs[kg*4+3][r] = v.w;
            }
#pragma unroll
            for (int it = 0; it < 4; ++it) {
                int idx = t + 256 * it, c = idx & 63, kg = idx >> 6;
                float4 v = *reinterpret_cast<const float4*>(
                    embed + (size_t)(jc * BN + c) * DIM + dc * DK + kg * 4);
                es[kg*4+0][c] = v.x; es[kg*4+1][c] = v.y; es[kg*4+2][c] = v.z; es[kg*4+3][c] = v.w;
            }
            __syncthreads();
#pragma unroll
            for (int k = 0; k < DK; ++k) {
                float4 a = *reinterpret_cast<const float4*>(&xs[k][ty * 4]);
                float4 b = *reinterpret_cast<const float4*>(&es[k][tx * 4]);
                float arr[4] = {a.x, a.y, a.z, a.w}, bc[4] = {b.x, b.y, b.z, b.w};
#pragma unroll
                for (int r = 0; r < 4; ++r)
#pragma unroll
                    for (int c = 0; c < 4; ++c) acc[r][c] = fmaf(arr[r], bc[c], acc[r][c]);
            }
        }
        float4 eq = *reinterpret_cast<const float4*>(esq + jc * BN + tx * 4);
        float eqa[4] = {eq.x, eq.y, eq.z, eq.w};
#pragma unroll
        for (int c = 0; c < 4; ++c) {
            int j = jc * BN + tx * 4 + c;
#pragma unroll
            for (int r = 0; r < 4; ++r) {
                float s = fmaf(-2.0f, acc[r][c], eqa[c]);
                if (s < minv[r]) { min2v[r] = minv[r]; minv[r] = s; mini[r] = j; }
                else if (s < min2v[r]) { min2v[r] = s; }
            }
        }
    }
#pragma unroll
    for (int r = 0; r < 4; ++r) {
        float v1 = minv[r]; int i1 = mini[r]; float v2 = min2v[r];
#pragma unroll
        for (int m = 1; m < 16; m <<= 1) {
            float ov1 = __shfl_xor(v1, m, 64); int oi1 = __shfl_xor(i1, m, 64);
            float ov2 = __shfl_xor(v2, m, 64);
            float nv2 = fminf(fmaxf(v1, ov1), fminf(v2, ov2));
            if (ov1 < v1 || (ov1 == v1 && oi1 < i1)) { v1 = ov1; i1 = oi1; }
            v2 = nv2;
        }
        minv[r] = v1; mini[r] = i1; min2v[r] = v2;
    }
    const size_t IOFF = (size_t)N * DIM, ROFF = IOFF + (size_t)N;
#pragma unroll
    for (int r = 0; r < 4; ++r) {
        int row = row0 + ty * 4 + r, idx = mini[r];
        if (tx == 0) {
            out[IOFF + row] = (float)idx;
            if (min2v[r] - minv[r] < MARGIN) { int p = atomicAdd(&nflag, 1); flr[p] = ty * 4 + r; }
        }
#pragma unroll
        for (int g = 0; g < 4; ++g) {
            int d0 = tx * 16 + g * 4;
            float4 e  = *reinterpret_cast<const float4*>(embed + (size_t)idx * DIM + d0);
            float4 xv = *reinterpret_cast<const float4*>(x + (size_t)row * DIM + d0);
            *reinterpret_cast<float4*>(out + (size_t)row * DIM + d0) = e;
            float4 rr = make_float4(e.x - xv.x, e.y - xv.y, e.z - xv.z, e.w - xv.w);
            *reinterpret_cast<float4*>(out + ROFF + (size_t)row * DIM + d0) = rr;
        }
    }
    __syncthreads();
    const int nf = nflag;
    for (int f = 0; f < nf; ++f) {
        const int row = row0 + flr[f];
        if (t < 64) {
            float4 v = *reinterpret_cast<const float4*>(x + (size_t)row * DIM + t * 4);
            xrow[t*4+0] = v.x; xrow[t*4+1] = v.y; xrow[t*4+2] = v.z; xrow[t*4+3] = v.w;
        }
        __syncthreads();
        double v1 = DBL_MAX, v2 = DBL_MAX; int i1 = 0x7fffffff, i2 = 0x7fffffff;
#pragma unroll
        for (int jj = 0; jj < 4; ++jj) {
            const int j = t * 4 + jj;
            const float* e = embed + (size_t)j * DIM;
            double xe = 0.0, ee = 0.0;
            for (int kg = 0; kg < DIM / 4; ++kg) {
                float4 ev = *reinterpret_cast<const float4*>(e + kg * 4);
                double e0 = ev.x, e1 = ev.y, e2 = ev.z, e3 = ev.w;
                xe += e0*(double)xrow[kg*4+0] + e1*(double)xrow[kg*4+1]
                    + e2*(double)xrow[kg*4+2] + e3*(double)xrow[kg*4+3];
                ee += e0*e0 + e1*e1 + e2*e2 + e3*e3;
            }
            double d = ee - 2.0 * xe;
            if (d < v1 || (d == v1 && j < i1)) { v2 = v1; i2 = i1; v1 = d; i1 = j; }
            else if (d < v2 || (d == v2 && j < i2)) { v2 = d; i2 = j; }
        }
        rv1[t] = v1; ri1[t] = i1; rv2[t] = v2; ri2[t] = i2;
        __syncthreads();
        for (int s = 128; s > 0; s >>= 1) {
            if (t < s) {
                double a1 = rv1[t], a2 = rv2[t]; int k1 = ri1[t], k2 = ri2[t];
                double b1 = rv1[t+s], b2 = rv2[t+s]; int j1 = ri1[t+s], j2 = ri2[t+s];
                double w1, w2; int m1, m2;
                bool bfirst = (b1 < a1) || (b1 == a1 && j1 < k1);
                if (bfirst) { w1 = b1; m1 = j1;
                    if (a1 < b2 || (a1 == b2 && k1 < j2)) { w2 = a1; m2 = k1; } else { w2 = b2; m2 = j2; }
                } else { w1 = a1; m1 = k1;
                    if (b1 < a2 || (b1 == a2 && j1 < k2)) { w2 = b1; m2 = j1; } else { w2 = a2; m2 = k2; }
                }
                rv1[t] = w1; ri1[t] = m1; rv2[t] = w2; ri2[t] = m2;
            }
            __syncthreads();
        }
        int idx = ri1[0];
        const double gap = rv2[0] - rv1[0];
#if PREFER_LOWER
        if (gap < EPS_TIE && ri2[0] < ri1[0]) idx = ri2[0];
#else
        if (gap < EPS_TIE && ri2[0] > ri1[0]) idx = ri2[0];
#endif
        if (t == 0) out[IOFF + row] = (float)idx;
        if (t < 64) {
            int d0 = t * 4;
            float4 e  = *reinterpret_cast<const float4*>(embed + (size_t)idx * DIM + d0);
            float4 xv = *reinterpret_cast<const float4*>(x + (size_t)row * DIM + d0);
            *reinterpret_cast<float4*>(out + (size_t)row * DIM + d0) = e;
            float4 rr = make_float4(e.x - xv.x, e.y - xv.y, e.z - xv.z, e.w - xv.w);
            *reinterpret_cast<float4*>(out + ROFF + (size_t)row * DIM + d0) = rr;
        }
        __syncthreads();
    }
}

extern "C" void kernel_launch(void* const* d_in, const int* in_sizes, int n_in,
                              void* d_out, int out_size, void* d_ws, size_t ws_size,
                              hipStream_t stream) {
    const float* x     = (const float*)d_in[0];
    const float* embed = (const float*)d_in[1];
    float* out = (float*)d_out;
    const int N = in_sizes[0] / DIM;   // 65536
    const int K = in_sizes[1] / DIM;   // 1024

    // ws layout (MFMA path): [0,4KB) esq | [4KB, +512KB) ehi | [+512KB, +512KB) elo
    float* esq = (float*)d_ws;
    unsigned short* ehi = (unsigned short*)((char*)d_ws + 4096);
    unsigned short* elo = (unsigned short*)((char*)d_ws + 4096 + 524288);
    const size_t need = 4096 + 2 * 524288;

    esq_kernel<<<K, 64, 0, stream>>>(embed, esq);
    if (ws_size >= need) {
        efrag_kernel<<<(K / 16) * 8, 64, 0, stream>>>(embed, ehi, elo);
        vq_mfma_kernel<<<N / ROWS, 256, 0, stream>>>(x, embed, ehi, elo, esq, out, N, K);
    } else {
        vq_argmin_kernel<<<N / BM, 256, 0, stream>>>(x, embed, esq, out, N, K);
    }
}

// Round 11
// 462.714 us; speedup vs baseline: 1.5712x; 1.2588x over previous
//
#include <hip/hip_runtime.h>
#include <math.h>
#include <float.h>

#define DIM 256
#define MARGIN 0.125f
// Tie policy (verified PASS R6-R10 — do not change):
#define EPS_TIE 1e-4
#define PREFER_LOWER 1

#define ROWS 64   // rows per block (MFMA path): 4 waves x 16 rows each

typedef __attribute__((ext_vector_type(8))) short short8;   // 8 bf16 = 4 VGPR
typedef __attribute__((ext_vector_type(4))) float f32x4;    // MFMA acc / vec4

__device__ __forceinline__ unsigned short f32_to_bf16_rne(float f) {
    unsigned int u = __float_as_uint(f);
    u += 0x7fffu + ((u >> 16) & 1u);
    return (unsigned short)(u >> 16);
}
__device__ __forceinline__ float bf16_to_f32(unsigned short h) {
    return __uint_as_float((unsigned int)h << 16);
}

// streaming (non-temporal) vec4 access: keep B/embed hot in L2
__device__ __forceinline__ f32x4 nt_load4(const float* p) {
    return __builtin_nontemporal_load((const f32x4*)p);
}
__device__ __forceinline__ void nt_store4(float* p, f32x4 v) {
    __builtin_nontemporal_store(v, (f32x4*)p);
}

// async global->LDS, 16B/lane: LDS dest = wave-uniform base + lane*16 (HW rule)
__device__ __forceinline__ void stage16(const void* gsrc, void* ldst) {
    __builtin_amdgcn_global_load_lds(
        (const __attribute__((address_space(1))) unsigned int*)gsrc,
        (__attribute__((address_space(3))) unsigned int*)ldst,
        16, 0, 0);
}

// |e_j|^2 (fast pass only needs approx); one wave per codebook row
__global__ void esq_kernel(const float* __restrict__ embed, float* __restrict__ esq) {
    const int j = blockIdx.x;
    const int lane = threadIdx.x;  // 64
    float4 v = *reinterpret_cast<const float4*>(embed + (size_t)j * DIM + lane * 4);
    float s = v.x * v.x + v.y * v.y + v.z * v.z + v.w * v.w;
#pragma unroll
    for (int m = 32; m >= 1; m >>= 1) s += __shfl_xor(s, m, 64);
    if (lane == 0) esq[j] = s;
}

// embed -> fragment-major bf16 hi/lo for mfma_f32_16x16x32_bf16 B operand.
// Block b = ct*8 + s (ct: 16-col tile 0..63, s: 32-k step 0..7). Lane l holds
// col = ct*16 + (l&15), k = s*32 + (l>>4)*8 + i  (i=0..7), stored contiguous.
__global__ void efrag_kernel(const float* __restrict__ embed,
                             unsigned short* __restrict__ ehi,
                             unsigned short* __restrict__ elo) {
    const int b = blockIdx.x;          // 0..511
    const int l = threadIdx.x;         // 0..63
    const int ct = b >> 3, s = b & 7;
    const int col = ct * 16 + (l & 15);
    const int kb  = s * 32 + (l >> 4) * 8;
    const float* src = embed + (size_t)col * DIM + kb;
    float4 v0 = *reinterpret_cast<const float4*>(src);
    float4 v1 = *reinterpret_cast<const float4*>(src + 4);
    float vv[8] = {v0.x, v0.y, v0.z, v0.w, v1.x, v1.y, v1.z, v1.w};
    unsigned short hh[8], ll[8];
#pragma unroll
    for (int i = 0; i < 8; ++i) {
        unsigned short h = f32_to_bf16_rne(vv[i]);
        hh[i] = h;
        ll[i] = f32_to_bf16_rne(vv[i] - bf16_to_f32(h));
    }
    size_t base = ((size_t)b * 64 + l) * 8;
#pragma unroll
    for (int i = 0; i < 8; ++i) { ehi[base + i] = hh[i]; elo[base + i] = ll[i]; }
}

// ---- MFMA fast pass: 4 waves x 16 rows, B LDS-staged, 2 k-steps/barrier ----
// Register budget: ahi/alo 64 + acc 16 + transients ~80 -> ~180 VGPR.
// amdgpu_waves_per_eu(2,2) pins the allocator to a 256-VGPR budget (2 waves/EU)
// so the A fragments actually stay resident (R7-R10 spilled at a 128 target).
__global__ __launch_bounds__(256) __attribute__((amdgpu_waves_per_eu(2, 2))) void
vq_mfma_kernel(const float* __restrict__ x, const float* __restrict__ embed,
               const unsigned short* __restrict__ ehi,
               const unsigned short* __restrict__ elo,
               const float* __restrict__ esq, float* __restrict__ out,
               int N, int K) {
    __shared__ unsigned short bfrag[2][4][2][2][512]; // [buf][ct][ss][hi/lo][64x8] = 32 KB
    __shared__ float  esq_lds[1024];
    __shared__ double rv1[256], rv2[256];
    __shared__ int    ri1[256], ri2[256];
    __shared__ float  xrow[DIM];
    __shared__ int    flr[ROWS];
    __shared__ int    nflag;

    const int t  = threadIdx.x;
    const int w  = t >> 6;       // wave 0..3 (stages ct=w; owns 16 rows)
    const int l  = t & 63;
    const int ar = l & 15;       // A-row / B-col / C-col lane field
    const int ag = l >> 4;       // k-group / C-row-group lane field
    const int row0  = blockIdx.x * ROWS;
    const int wrow0 = row0 + w * 16;

    if (t == 0) nflag = 0;
    for (int i = t; i < 1024; i += 256) esq_lds[i] = esq[i];

    // A fragments resident: 8 k-steps, hi+lo (64 VGPR); NT loads
    short8 ahi[8], alo[8];
#pragma unroll
    for (int s = 0; s < 8; ++s) {
        const float* src = x + (size_t)(wrow0 + ar) * DIM + s * 32 + ag * 8;
        f32x4 v0 = nt_load4(src);
        f32x4 v1 = nt_load4(src + 4);
        float vv[8] = {v0[0], v0[1], v0[2], v0[3], v1[0], v1[1], v1[2], v1[3]};
#pragma unroll
        for (int i = 0; i < 8; ++i) {
            unsigned short h = f32_to_bf16_rne(vv[i]);
            ahi[s][i] = (short)h;
            alo[s][i] = (short)f32_to_bf16_rne(vv[i] - bf16_to_f32(h));
        }
    }

    // stage phase P (k-steps 2P, 2P+1) of chunk JC for ct=w into buffer CB
#define STAGE2(CB, JC, P) do {                                                  \
        size_t g0_ = (((size_t)((JC) * 4 + w) * 8 + 2 * (P)) * 64 + l) * 8;     \
        stage16(ehi + g0_,       &bfrag[CB][w][0][0][0]);                       \
        stage16(elo + g0_,       &bfrag[CB][w][0][1][0]);                       \
        stage16(ehi + g0_ + 512, &bfrag[CB][w][1][0][0]);                       \
        stage16(elo + g0_ + 512, &bfrag[CB][w][1][1][0]);                       \
    } while (0)

    // prologue: stage (jc=0,p=0) into buf 0; barrier publishes esq_lds/nflag too
    STAGE2(0, 0, 0);
    __syncthreads();

    float minv[4], min2v[4]; int mini[4];
#pragma unroll
    for (int i = 0; i < 4; ++i) { minv[i] = INFINITY; min2v[i] = INFINITY; mini[i] = 0; }

    f32x4 acc[4];
#pragma unroll
    for (int ct = 0; ct < 4; ++ct) acc[ct] = (f32x4)0.0f;

    for (int jc = 0; jc < 16; ++jc) {
#pragma unroll
        for (int p = 0; p < 4; ++p) {          // 4 phases x 2 k-steps
            const int cb = p & 1;
            if (p < 3)            STAGE2(cb ^ 1, jc, p + 1);
            else if (jc < 15)     STAGE2(cb ^ 1, jc + 1, 0);
#pragma unroll
            for (int ss = 0; ss < 2; ++ss) {
                const int s = p * 2 + ss;
                short8 bh[4], bl[4];
#pragma unroll
                for (int ct = 0; ct < 4; ++ct) {
                    bh[ct] = *reinterpret_cast<const short8*>(&bfrag[cb][ct][ss][0][l * 8]);
                    bl[ct] = *reinterpret_cast<const short8*>(&bfrag[cb][ct][ss][1][l * 8]);
                }
#pragma unroll
                for (int ct = 0; ct < 4; ++ct) {
                    acc[ct] = __builtin_amdgcn_mfma_f32_16x16x32_bf16(ahi[s], bh[ct], acc[ct], 0, 0, 0);
                    acc[ct] = __builtin_amdgcn_mfma_f32_16x16x32_bf16(ahi[s], bl[ct], acc[ct], 0, 0, 0);
                    acc[ct] = __builtin_amdgcn_mfma_f32_16x16x32_bf16(alo[s], bh[ct], acc[ct], 0, 0, 0);
                }
            }
            __syncthreads();   // stage of buf^1 drained; reads of buf done
        }
        // jc epilogue: scores + per-lane top-2 (ct then jc ascending -> first-index)
#pragma unroll
        for (int ct = 0; ct < 4; ++ct) {
            const int col = jc * 64 + ct * 16 + ar;
            const float eq = esq_lds[col];
#pragma unroll
            for (int r = 0; r < 4; ++r) {
                float sc = fmaf(-2.0f, acc[ct][r], eq);
                if (sc < minv[r]) { min2v[r] = minv[r]; minv[r] = sc; mini[r] = col; }
                else if (sc < min2v[r]) min2v[r] = sc;
            }
            acc[ct] = (f32x4)0.0f;
        }
    }
#undef STAGE2

    // butterfly top-2 across the 16 ar lanes (masks 1,2,4,8); ties -> lower index
#pragma unroll
    for (int r = 0; r < 4; ++r) {
        float v1 = minv[r]; int i1 = mini[r]; float v2 = min2v[r];
#pragma unroll
        for (int m = 1; m < 16; m <<= 1) {
            float ov1 = __shfl_xor(v1, m, 64);
            int   oi1 = __shfl_xor(i1, m, 64);
            float ov2 = __shfl_xor(v2, m, 64);
            float nv2 = fminf(fmaxf(v1, ov1), fminf(v2, ov2));
            if (ov1 < v1 || (ov1 == v1 && oi1 < i1)) { v1 = ov1; i1 = oi1; }
            v2 = nv2;
        }
        minv[r] = v1; mini[r] = i1; min2v[r] = v2;
    }

    // outputs: [quantize | indices(as float) | residual]; NT streams
    const size_t IOFF = (size_t)N * DIM;
    const size_t ROFF = IOFF + (size_t)N;
#pragma unroll
    for (int r = 0; r < 4; ++r) {
        const int row = wrow0 + ag * 4 + r;
        const int idx = mini[r];
        if (ar == 0) {
            out[IOFF + row] = (float)idx;
            if (min2v[r] - minv[r] < MARGIN) {
                int p = atomicAdd(&nflag, 1);      // LDS atomic; p < ROWS
                flr[p] = row - row0;
            }
        }
#pragma unroll
        for (int q = 0; q < 4; ++q) {
            int d0 = ar * 16 + q * 4;
            f32x4 e  = *reinterpret_cast<const f32x4*>(embed + (size_t)idx * DIM + d0);
            f32x4 xv = nt_load4(x + (size_t)row * DIM + d0);
            nt_store4(out + (size_t)row * DIM + d0, e);
            nt_store4(out + ROFF + (size_t)row * DIM + d0, e - xv);
        }
    }

    // ---- exact (fp64) top-2 refinement + tie policy (R6-verified, unchanged) ----
    __syncthreads();
    const int nf = nflag;
    for (int f = 0; f < nf; ++f) {
        const int row = row0 + flr[f];
        if (t < 64) {
            float4 v = *reinterpret_cast<const float4*>(x + (size_t)row * DIM + t * 4);
            xrow[t * 4 + 0] = v.x; xrow[t * 4 + 1] = v.y;
            xrow[t * 4 + 2] = v.z; xrow[t * 4 + 3] = v.w;
        }
        __syncthreads();

        double v1 = DBL_MAX, v2 = DBL_MAX; int i1 = 0x7fffffff, i2 = 0x7fffffff;
#pragma unroll
        for (int jj = 0; jj < 4; ++jj) {
            const int j = t * 4 + jj;
            const float* e = embed + (size_t)j * DIM;
            double xe = 0.0, ee = 0.0;
            for (int kg = 0; kg < DIM / 4; ++kg) {
                float4 ev = *reinterpret_cast<const float4*>(e + kg * 4);
                double e0 = ev.x, e1 = ev.y, e2 = ev.z, e3 = ev.w;
                xe += e0 * (double)xrow[kg * 4 + 0] + e1 * (double)xrow[kg * 4 + 1]
                    + e2 * (double)xrow[kg * 4 + 2] + e3 * (double)xrow[kg * 4 + 3];
                ee += e0 * e0 + e1 * e1 + e2 * e2 + e3 * e3;
            }
            double d = ee - 2.0 * xe;            // shift-invariant score
            if (d < v1 || (d == v1 && j < i1)) { v2 = v1; i2 = i1; v1 = d; i1 = j; }
            else if (d < v2 || (d == v2 && j < i2)) { v2 = d; i2 = j; }
        }
        rv1[t] = v1; ri1[t] = i1; rv2[t] = v2; ri2[t] = i2;
        __syncthreads();
        for (int s = 128; s > 0; s >>= 1) {
            if (t < s) {
                double a1 = rv1[t],     a2 = rv2[t];     int k1 = ri1[t],     k2 = ri2[t];
                double b1 = rv1[t + s], b2 = rv2[t + s]; int j1 = ri1[t + s], j2 = ri2[t + s];
                double w1, w2; int m1, m2;
                bool bfirst = (b1 < a1) || (b1 == a1 && j1 < k1);
                if (bfirst) {
                    w1 = b1; m1 = j1;
                    if (a1 < b2 || (a1 == b2 && k1 < j2)) { w2 = a1; m2 = k1; }
                    else                                   { w2 = b2; m2 = j2; }
                } else {
                    w1 = a1; m1 = k1;
                    if (b1 < a2 || (b1 == a2 && j1 < k2)) { w2 = b1; m2 = j1; }
                    else                                   { w2 = a2; m2 = k2; }
                }
                rv1[t] = w1; ri1[t] = m1; rv2[t] = w2; ri2[t] = m2;
            }
            __syncthreads();
        }
        int idx = ri1[0];
        {
            const double gap = rv2[0] - rv1[0];
#if PREFER_LOWER
            if (gap < EPS_TIE && ri2[0] < ri1[0]) idx = ri2[0];
#else
            if (gap < EPS_TIE && ri2[0] > ri1[0]) idx = ri2[0];
#endif
        }
        if (t == 0) out[IOFF + row] = (float)idx;
        if (t < 64) {
            int d0 = t * 4;
            float4 e  = *reinterpret_cast<const float4*>(embed + (size_t)idx * DIM + d0);
            float4 xv = *reinterpret_cast<const float4*>(x + (size_t)row * DIM + d0);
            *reinterpret_cast<float4*>(out + (size_t)row * DIM + d0) = e;
            float4 rr = make_float4(e.x - xv.x, e.y - xv.y, e.z - xv.z, e.w - xv.w);
            *reinterpret_cast<float4*>(out + ROFF + (size_t)row * DIM + d0) = rr;
        }
        __syncthreads();
    }
}

// ================= fallback: R6-verified VALU path (used if ws too small) ====
#define BM 64
#define BN 64
#define DK 64
__global__ __launch_bounds__(256, 4)
void vq_argmin_kernel(const float* __restrict__ x, const float* __restrict__ embed,
                      const float* __restrict__ esq, float* __restrict__ out,
                      int N, int K) {
    __shared__ float xs[DK][BM];
    __shared__ float es[DK][BN];
    __shared__ double rv1[256], rv2[256];
    __shared__ int    ri1[256], ri2[256];
    __shared__ float  xrow[DIM];
    __shared__ int    flr[BM];
    __shared__ int    nflag;

    const int t = threadIdx.x;
    const int tx = t & 15, ty = t >> 4;
    const int row0 = blockIdx.x * BM;
    if (t == 0) nflag = 0;

    float minv[4], min2v[4]; int mini[4];
#pragma unroll
    for (int r = 0; r < 4; ++r) { minv[r] = INFINITY; min2v[r] = INFINITY; mini[r] = 0; }

    for (int jc = 0; jc < K / BN; ++jc) {
        float acc[4][4];
#pragma unroll
        for (int r = 0; r < 4; ++r)
#pragma unroll
            for (int c = 0; c < 4; ++c) acc[r][c] = 0.0f;
        for (int dc = 0; dc < DIM / DK; ++dc) {
            __syncthreads();
#pragma unroll
            for (int it = 0; it < 4; ++it) {
                int idx = t + 256 * it, r = idx & 63, kg = idx >> 6;
                float4 v = *reinterpret_cast<const float4*>(
                    x + (size_t)(row0 + r) * DIM + dc * DK + kg * 4);
                xs[kg*4+0][r] = v.x; xs[kg*4+1][r] = v.y; xs[kg*4+2][r] = v.z; xs[kg*4+3][r] = v.w;
            }
#pragma unroll
            for (int it = 0; it < 4; ++it) {
                int idx = t + 256 * it, c = idx & 63, kg = idx >> 6;
                float4 v = *reinterpret_cast<const float4*>(
                    embed + (size_t)(jc * BN + c) * DIM + dc * DK + kg * 4);
                es[kg*4+0][c] = v.x; es[kg*4+1][c] = v.y; es[kg*4+2][c] = v.z; es[kg*4+3][c] = v.w;
            }
            __syncthreads();
#pragma unroll
            for (int k = 0; k < DK; ++k) {
                float4 a = *reinterpret_cast<const float4*>(&xs[k][ty * 4]);
                float4 b = *reinterpret_cast<const float4*>(&es[k][tx * 4]);
                float arr[4] = {a.x, a.y, a.z, a.w}, bc[4] = {b.x, b.y, b.z, b.w};
#pragma unroll
                for (int r = 0; r < 4; ++r)
#pragma unroll
                    for (int c = 0; c < 4; ++c) acc[r][c] = fmaf(arr[r], bc[c], acc[r][c]);
            }
        }
        float4 eq = *reinterpret_cast<const float4*>(esq + jc * BN + tx * 4);
        float eqa[4] = {eq.x, eq.y, eq.z, eq.w};
#pragma unroll
        for (int c = 0; c < 4; ++c) {
            int j = jc * BN + tx * 4 + c;
#pragma unroll
            for (int r = 0; r < 4; ++r) {
                float s = fmaf(-2.0f, acc[r][c], eqa[c]);
                if (s < minv[r]) { min2v[r] = minv[r]; minv[r] = s; mini[r] = j; }
                else if (s < min2v[r]) { min2v[r] = s; }
            }
        }
    }
#pragma unroll
    for (int r = 0; r < 4; ++r) {
        float v1 = minv[r]; int i1 = mini[r]; float v2 = min2v[r];
#pragma unroll
        for (int m = 1; m < 16; m <<= 1) {
            float ov1 = __shfl_xor(v1, m, 64); int oi1 = __shfl_xor(i1, m, 64);
            float ov2 = __shfl_xor(v2, m, 64);
            float nv2 = fminf(fmaxf(v1, ov1), fminf(v2, ov2));
            if (ov1 < v1 || (ov1 == v1 && oi1 < i1)) { v1 = ov1; i1 = oi1; }
            v2 = nv2;
        }
        minv[r] = v1; mini[r] = i1; min2v[r] = v2;
    }
    const size_t IOFF = (size_t)N * DIM, ROFF = IOFF + (size_t)N;
#pragma unroll
    for (int r = 0; r < 4; ++r) {
        int row = row0 + ty * 4 + r, idx = mini[r];
        if (tx == 0) {
            out[IOFF + row] = (float)idx;
            if (min2v[r] - minv[r] < MARGIN) { int p = atomicAdd(&nflag, 1); flr[p] = ty * 4 + r; }
        }
#pragma unroll
        for (int g = 0; g < 4; ++g) {
            int d0 = tx * 16 + g * 4;
            float4 e  = *reinterpret_cast<const float4*>(embed + (size_t)idx * DIM + d0);
            float4 xv = *reinterpret_cast<const float4*>(x + (size_t)row * DIM + d0);
            *reinterpret_cast<float4*>(out + (size_t)row * DIM + d0) = e;
            float4 rr = make_float4(e.x - xv.x, e.y - xv.y, e.z - xv.z, e.w - xv.w);
            *reinterpret_cast<float4*>(out + ROFF + (size_t)row * DIM + d0) = rr;
        }
    }
    __syncthreads();
    const int nf = nflag;
    for (int f = 0; f < nf; ++f) {
        const int row = row0 + flr[f];
        if (t < 64) {
            float4 v = *reinterpret_cast<const float4*>(x + (size_t)row * DIM + t * 4);
            xrow[t*4+0] = v.x; xrow[t*4+1] = v.y; xrow[t*4+2] = v.z; xrow[t*4+3] = v.w;
        }
        __syncthreads();
        double v1 = DBL_MAX, v2 = DBL_MAX; int i1 = 0x7fffffff, i2 = 0x7fffffff;
#pragma unroll
        for (int jj = 0; jj < 4; ++jj) {
            const int j = t * 4 + jj;
            const float* e = embed + (size_t)j * DIM;
            double xe = 0.0, ee = 0.0;
            for (int kg = 0; kg < DIM / 4; ++kg) {
                float4 ev = *reinterpret_cast<const float4*>(e + kg * 4);
                double e0 = ev.x, e1 = ev.y, e2 = ev.z, e3 = ev.w;
                xe += e0*(double)xrow[kg*4+0] + e1*(double)xrow[kg*4+1]
                    + e2*(double)xrow[kg*4+2] + e3*(double)xrow[kg*4+3];
                ee += e0*e0 + e1*e1 + e2*e2 + e3*e3;
            }
            double d = ee - 2.0 * xe;
            if (d < v1 || (d == v1 && j < i1)) { v2 = v1; i2 = i1; v1 = d; i1 = j; }
            else if (d < v2 || (d == v2 && j < i2)) { v2 = d; i2 = j; }
        }
        rv1[t] = v1; ri1[t] = i1; rv2[t] = v2; ri2[t] = i2;
        __syncthreads();
        for (int s = 128; s > 0; s >>= 1) {
            if (t < s) {
                double a1 = rv1[t], a2 = rv2[t]; int k1 = ri1[t], k2 = ri2[t];
                double b1 = rv1[t+s], b2 = rv2[t+s]; int j1 = ri1[t+s], j2 = ri2[t+s];
                double w1, w2; int m1, m2;
                bool bfirst = (b1 < a1) || (b1 == a1 && j1 < k1);
                if (bfirst) { w1 = b1; m1 = j1;
                    if (a1 < b2 || (a1 == b2 && k1 < j2)) { w2 = a1; m2 = k1; } else { w2 = b2; m2 = j2; }
                } else { w1 = a1; m1 = k1;
                    if (b1 < a2 || (b1 == a2 && j1 < k2)) { w2 = b1; m2 = j1; } else { w2 = a2; m2 = k2; }
                }
                rv1[t] = w1; ri1[t] = m1; rv2[t] = w2; ri2[t] = m2;
            }
            __syncthreads();
        }
        int idx = ri1[0];
        const double gap = rv2[0] - rv1[0];
#if PREFER_LOWER
        if (gap < EPS_TIE && ri2[0] < ri1[0]) idx = ri2[0];
#else
        if (gap < EPS_TIE && ri2[0] > ri1[0]) idx = ri2[0];
#endif
        if (t == 0) out[IOFF + row] = (float)idx;
        if (t < 64) {
            int d0 = t * 4;
            float4 e  = *reinterpret_cast<const float4*>(embed + (size_t)idx * DIM + d0);
            float4 xv = *reinterpret_cast<const float4*>(x + (size_t)row * DIM + d0);
            *reinterpret_cast<float4*>(out + (size_t)row * DIM + d0) = e;
            float4 rr = make_float4(e.x - xv.x, e.y - xv.y, e.z - xv.z, e.w - xv.w);
            *reinterpret_cast<float4*>(out + ROFF + (size_t)row * DIM + d0) = rr;
        }
        __syncthreads();
    }
}

extern "C" void kernel_launch(void* const* d_in, const int* in_sizes, int n_in,
                              void* d_out, int out_size, void* d_ws, size_t ws_size,
                              hipStream_t stream) {
    const float* x     = (const float*)d_in[0];
    const float* embed = (const float*)d_in[1];
    float* out = (float*)d_out;
    const int N = in_sizes[0] / DIM;   // 65536
    const int K = in_sizes[1] / DIM;   // 1024

    // ws layout (MFMA path): [0,4KB) esq | [4KB, +512KB) ehi | [+512KB, +512KB) elo
    float* esq = (float*)d_ws;
    unsigned short* ehi = (unsigned short*)((char*)d_ws + 4096);
    unsigned short* elo = (unsigned short*)((char*)d_ws + 4096 + 524288);
    const size_t need = 4096 + 2 * 524288;

    esq_kernel<<<K, 64, 0, stream>>>(embed, esq);
    if (ws_size >= need) {
        efrag_kernel<<<(K / 16) * 8, 64, 0, stream>>>(embed, ehi, elo);
        vq_mfma_kernel<<<N / ROWS, 256, 0, stream>>>(x, embed, ehi, elo, esq, out, N, K);
    } else {
        vq_argmin_kernel<<<N / BM, 256, 0, stream>>>(x, embed, esq, out, N, K);
    }
}